// Round 3
// baseline (696.866 us; speedup 1.0000x reference)
//
#include <hip/hip_runtime.h>

// Problem constants
constexpr int Nn = 4096, Fc = 128;
constexpr int Rr = 32, Hh = 4, Dd = 32;
constexpr int BT = 96;                          // B*T
constexpr float SCALE = 0.17677669529663687f;   // 1/sqrt(32)

// Workspace layout (float offsets)
constexpr size_t OFF_V1  = 0;                               // [BT][H][R][D] f32
constexpr size_t OFF_Z   = (size_t)BT * Hh * Rr * Dd;       // [BT][H][R]   f32
constexpr size_t OFF_BQK = OFF_Z + (size_t)BT * Hh * Rr;    // [H*R]        f32
constexpr size_t OFF_U   = OFF_BQK + 128;                   // param bf16 region

// U (ushort) offsets: WK hi (fused key·Wq), Wv hi, Wv lo
constexpr int U_WKHI = 0, U_WVHI = 16384, U_WVLO = 32768;

using short8  = __attribute__((ext_vector_type(8))) short;
using floatx4 = __attribute__((ext_vector_type(4))) float;

__device__ inline ushort f2bf(float f) {
    union { float f; unsigned u; } c{f};
    unsigned r = c.u + 0x7fffu + ((c.u >> 16) & 1u);  // RNE
    return (ushort)(r >> 16);
}
__device__ inline float bf2f(ushort u) {
    union { unsigned u; float f; } c{(unsigned)u << 16};
    return c.f;
}

// ---------------------------------------------------------------------------
// kprep: WK[h*32+r][f] = sum_d Wq[h*32+d][f]*key[r][h][d]  (bf16 hi)
//        Wv hi/lo split; bqk[h*32+r] = sum_d bq[h*32+d]*key[r][h][d] (f32)
// ---------------------------------------------------------------------------
__global__ void kprep(const float* __restrict__ Wq, const float* __restrict__ bq,
                      const float* __restrict__ Wv, const float* __restrict__ key,
                      ushort* __restrict__ U, float* __restrict__ bqk)
{
    const int idx = blockIdx.x * 256 + threadIdx.x;
    if (idx < 16384) {
        const int hr = idx >> 7, f = idx & 127;
        const int h = hr >> 5, r = hr & 31;
        float s = 0.f;
#pragma unroll
        for (int d = 0; d < 32; d++)
            s += Wq[(h * 32 + d) * 128 + f] * key[(r * 4 + h) * 32 + d];
        U[U_WKHI + idx] = f2bf(s);
    } else if (idx < 32768) {
        const int o = idx - 16384;
        const float v = Wv[o];
        const ushort h = f2bf(v);
        U[U_WVHI + o] = h;
        U[U_WVLO + o] = f2bf(v - bf2f(h));
    } else if (idx < 32768 + 128) {
        const int hr = idx - 32768;
        const int h = hr >> 5, r = hr & 31;
        float s = 0.f;
#pragma unroll
        for (int d = 0; d < 32; d++)
            s += bq[h * 32 + d] * key[(r * 4 + h) * 32 + d];
        bqk[hr] = s;
    }
}

// ---------------------------------------------------------------------------
// ka (pass A): NT=4 tiles of 64 nodes per block, register prefetch.
// Single-buffered x tile + per-wave eT/xvT scratch: LDS 54272 -> 3 blocks/CU
// (12 waves/CU; was 2 blocks/8 waves). Two barriers/iter; prefetch issued
// after barrier 2 so it flies through the whole epilogue.
// ---------------------------------------------------------------------------
__global__ __launch_bounds__(256, 3)
void ka(const float* __restrict__ x, const float* __restrict__ bv,
        const ushort* __restrict__ U, const float* __restrict__ bqk,
        float* __restrict__ v1, float* __restrict__ Z)
{
    // xh [64][136] bf16 17408 | per-wave: eT [32][68] 4352 + xvT [32][72] 4608
    __shared__ __align__(16) char lds[54272];
    ushort* xh = (ushort*)lds;

    const int t = threadIdx.x;
    const int w = t >> 6, lane = t & 63;
    const int quad = lane >> 4, l15 = lane & 15;
    const int bt = blockIdx.y;
    constexpr int NT = 4;

    char* wsc = lds + 17408 + w * 8960;
    ushort* eT  = (ushort*)wsc;           // [32 r][68 n] bf16 (stride 68: 136B, 16B-mult? 136=8*17 -> b128 ok at even rows... see reads below)
    ushort* xvT = (ushort*)(wsc + 4352);  // [32 d][72 n] bf16

    const ushort* WKh = U + U_WKHI;
    const ushort* Wvh = U + U_WVHI;

    float bvv[2], bqkv[2];
#pragma unroll
    for (int i = 0; i < 2; i++) {
        bvv[i]  = bv[32 * w + 16 * i + l15];
        bqkv[i] = bqk[32 * w + 16 * i + l15];
    }

    floatx4 accV1[2][2];
#pragma unroll
    for (int i = 0; i < 2; i++)
#pragma unroll
        for (int j = 0; j < 2; j++) accV1[i][j] = (floatx4)0.f;
    float zacc[2] = {0.f, 0.f};

    const float* xbase = x + ((size_t)bt * Nn + blockIdx.x * (NT * 64)) * Fc;

    // prologue: tile 0 -> regs
    float4 xr[8];
#pragma unroll
    for (int i = 0; i < 8; i++) xr[i] = ((const float4*)xbase)[i * 256 + t];

#pragma unroll 1
    for (int it = 0; it < NT; ++it) {
        // regs -> LDS (waits on the prefetch issued last iteration)
#pragma unroll
        for (int i = 0; i < 8; i++) {
            const int idx = i * 256 + t;
            const int row = idx >> 5, c4 = idx & 31;
            float4 v = xr[i];
            ushort4 hv;
            hv.x = f2bf(v.x); hv.y = f2bf(v.y); hv.z = f2bf(v.z); hv.w = f2bf(v.w);
            *(ushort4*)&xh[row * 136 + c4 * 4] = hv;
        }
        __syncthreads();   // b1: tile staged

        floatx4 acca[4][2], accv[4][2];
#pragma unroll
        for (int mt = 0; mt < 4; mt++)
#pragma unroll
            for (int nt = 0; nt < 2; nt++) {
                acca[mt][nt] = (floatx4)0.f;
                accv[mt][nt] = (floatx4)0.f;
            }

#pragma unroll
        for (int kc = 0; kc < 4; kc++) {
            short8 ah[4];
#pragma unroll
            for (int mt = 0; mt < 4; mt++)
                ah[mt] = *(const short8*)&xh[(16 * mt + l15) * 136 + kc * 32 + quad * 8];
            short8 kb2[2], vb[2];
#pragma unroll
            for (int nt = 0; nt < 2; nt++) {
                const int off = (32 * w + 16 * nt + l15) * 128 + kc * 32 + quad * 8;
                kb2[nt] = *(const short8*)&WKh[off];
                vb[nt]  = *(const short8*)&Wvh[off];
            }
#pragma unroll
            for (int mt = 0; mt < 4; mt++)
#pragma unroll
                for (int nt = 0; nt < 2; nt++) {
                    acca[mt][nt] = __builtin_amdgcn_mfma_f32_16x16x32_bf16(ah[mt], kb2[nt], acca[mt][nt], 0, 0, 0);
                    accv[mt][nt] = __builtin_amdgcn_mfma_f32_16x16x32_bf16(ah[mt], vb[nt],  accv[mt][nt], 0, 0, 0);
                }
        }
        __syncthreads();   // b2: all xh reads done -> next iter may overwrite

        // issue next tile's loads: in flight through the whole epilogue
        if (it + 1 < NT) {
            const float4* xg = (const float4*)(xbase + (size_t)(it + 1) * 64 * Fc);
#pragma unroll
            for (int i = 0; i < 8; i++) xr[i] = xg[i * 256 + t];
        }

        // exp -> eT bf16 [r][n]; Z partials; per-n rowsum partials in regs
        float sloc[4][4];
#pragma unroll
        for (int mt = 0; mt < 4; mt++)
#pragma unroll
            for (int reg = 0; reg < 4; reg++) {
                const int n = 16 * mt + 4 * quad + reg;
                const float e0 = __expf((acca[mt][0][reg] + bqkv[0]) * SCALE);
                const float e1 = __expf((acca[mt][1][reg] + bqkv[1]) * SCALE);
                eT[l15 * 68 + n]        = f2bf(e0);   // r = l15
                eT[(16 + l15) * 68 + n] = f2bf(e1);   // r = 16 + l15
                zacc[0] += e0; zacc[1] += e1;
                sloc[mt][reg] = e0 + e1;
            }
        // butterfly over the 16-lane group: sloc becomes sum_r e[n][r]
#pragma unroll
        for (int m = 1; m < 16; m <<= 1)
#pragma unroll
            for (int mt = 0; mt < 4; mt++)
#pragma unroll
                for (int reg = 0; reg < 4; reg++)
                    sloc[mt][reg] += __shfl_xor(sloc[mt][reg], m);

        // xv -> xvT [d][n] bf16, pre-scaled by 1/rowsum (lane owns its n's sum)
#pragma unroll
        for (int mt = 0; mt < 4; mt++)
#pragma unroll
            for (int reg = 0; reg < 4; reg++) {
                const int n = 16 * mt + 4 * quad + reg;
                const float sw = 1.f / sloc[mt][reg];
#pragma unroll
                for (int nt = 0; nt < 2; nt++)
                    xvT[(16 * nt + l15) * 72 + n] =
                        f2bf((accv[mt][nt][reg] + bvv[nt]) * sw);
            }

        // v1[r][d] += sum_n eT[r][n] * xvT[d][n]
#pragma unroll
        for (int kn = 0; kn < 2; kn++) {
            short8 ae[2], bx[2];
#pragma unroll
            for (int i = 0; i < 2; i++) {
                ae[i] = *(const short8*)&eT[(16 * i + l15) * 68 + kn * 32 + quad * 8];
                bx[i] = *(const short8*)&xvT[(16 * i + l15) * 72 + kn * 32 + quad * 8];
            }
#pragma unroll
            for (int mt = 0; mt < 2; mt++)
#pragma unroll
                for (int nt = 0; nt < 2; nt++)
                    accV1[mt][nt] = __builtin_amdgcn_mfma_f32_16x16x32_bf16(ae[mt], bx[nt], accV1[mt][nt], 0, 0, 0);
        }
    }

    // Z: reduce over quads, atomic once per col
#pragma unroll
    for (int rt = 0; rt < 2; rt++) {
        float zr = zacc[rt];
        zr += __shfl_xor(zr, 16);
        zr += __shfl_xor(zr, 32);
        if (quad == 0)
            atomicAdd(&Z[((size_t)bt * Hh + w) * Rr + 16 * rt + l15], zr);
    }
    float* v1b = v1 + ((size_t)bt * Hh + w) * Rr * Dd;
#pragma unroll
    for (int mt = 0; mt < 2; mt++)
#pragma unroll
        for (int nt = 0; nt < 2; nt++)
#pragma unroll
            for (int reg = 0; reg < 4; reg++)
                atomicAdd(&v1b[(16 * mt + 4 * quad + reg) * 32 + 16 * nt + l15],
                          accV1[mt][nt][reg]);
}

// ---------------------------------------------------------------------------
// kb (pass B): recompute attn + xv (hi/lo), v2 = expa @ (v1/Z) via MFMA.
// k2b folded in: each block builds its bf16 vbz fragment from v1/Z directly
// (16 L2 loads/lane, once per block). eS shrunk to [32][40] processed in two
// half-batches; out stored directly from C-layout (no f32 LDS roundtrip).
// LDS 45056 -> 3 blocks/CU.
// ---------------------------------------------------------------------------
__global__ __launch_bounds__(256, 3)
void kb(const float* __restrict__ x, const float* __restrict__ bv,
        const ushort* __restrict__ U, const float* __restrict__ bqk,
        const float* __restrict__ v1, const float* __restrict__ Z,
        const float* __restrict__ alpha, const float* __restrict__ beta,
        float* __restrict__ out)
{
    // xhi [64][136] 17408 | xlo 17408 | 4x per-wave eS [32][40] 2560
    __shared__ __align__(16) char lds[45056];
    ushort* xhi = (ushort*)lds;
    ushort* xlo = (ushort*)(lds + 17408);

    const int t = threadIdx.x;
    const int w = t >> 6, lane = t & 63;
    const int quad = lane >> 4, l15 = lane & 15;
    const int bt = blockIdx.y;
    constexpr int NT = 4;

    ushort* eS = (ushort*)(lds + 34816 + w * 2560);   // [32][40] bf16

    const ushort* WKh = U + U_WKHI;
    const ushort* Wvh = U + U_WVHI;
    const ushort* Wvl = U + U_WVLO;

    float bqkv[2], bvv[2];
#pragma unroll
    for (int i = 0; i < 2; i++) {
        bqkv[i] = bqk[32 * w + 16 * i + l15];
        bvv[i]  = bv[32 * w + 16 * i + l15];
    }

    // build vbz B-frag: vbz[dt] lane(q,l15) = bf16(v1[r=8q+j][d=16dt+l15]/Z[r])
    const float* v1h = v1 + ((size_t)bt * Hh + w) * Rr * Dd;
    const float* Zh  = Z + ((size_t)bt * Hh + w) * Rr;
    float zr8[8];
#pragma unroll
    for (int j = 0; j < 8; j++) zr8[j] = 1.f / Zh[8 * quad + j];
    short8 vbz[2];
#pragma unroll
    for (int dt = 0; dt < 2; dt++) {
        union { short8 s; unsigned u[4]; } uu;
#pragma unroll
        for (int jj = 0; jj < 4; jj++) {
            const float a0 = v1h[(8 * quad + 2 * jj) * 32 + 16 * dt + l15] * zr8[2 * jj];
            const float a1 = v1h[(8 * quad + 2 * jj + 1) * 32 + 16 * dt + l15] * zr8[2 * jj + 1];
            uu.u[jj] = ((unsigned)f2bf(a1) << 16) | f2bf(a0);
        }
        vbz[dt] = uu.s;
    }
    const float sa = 1.f / (1.f + __expf(-alpha[w]));
    const float sb = 1.f / (1.f + __expf(-beta[w]));

    const float* xbase = x + ((size_t)bt * Nn + blockIdx.x * (NT * 64)) * Fc;
    float* obase = out + ((size_t)bt * Nn + blockIdx.x * (NT * 64)) * Fc;

    float4 xr[8];
#pragma unroll
    for (int i = 0; i < 8; i++) xr[i] = ((const float4*)xbase)[i * 256 + t];

#pragma unroll 1
    for (int it = 0; it < NT; ++it) {
        // regs -> LDS hi/lo (waits on prefetch)
#pragma unroll
        for (int i = 0; i < 8; i++) {
            const int idx = i * 256 + t;
            const int row = idx >> 5, c4 = idx & 31;
            float4 v = xr[i];
            ushort h0 = f2bf(v.x), h1 = f2bf(v.y), h2 = f2bf(v.z), h3 = f2bf(v.w);
            ushort4 hv; hv.x = h0; hv.y = h1; hv.z = h2; hv.w = h3;
            ushort4 lv; lv.x = f2bf(v.x - bf2f(h0)); lv.y = f2bf(v.y - bf2f(h1));
            lv.z = f2bf(v.z - bf2f(h2)); lv.w = f2bf(v.w - bf2f(h3));
            *(ushort4*)&xhi[row * 136 + c4 * 4] = hv;
            *(ushort4*)&xlo[row * 136 + c4 * 4] = lv;
        }
        __syncthreads();   // b1

        floatx4 acca[4][2], accv[4][2];
#pragma unroll
        for (int mt = 0; mt < 4; mt++)
#pragma unroll
            for (int nt = 0; nt < 2; nt++) {
                acca[mt][nt] = (floatx4)0.f;
                accv[mt][nt] = (floatx4)0.f;
            }

#pragma unroll
        for (int kc = 0; kc < 4; kc++) {
            short8 ahi[4], alo[4];
#pragma unroll
            for (int mt = 0; mt < 4; mt++) {
                const int ro = (16 * mt + l15) * 136 + kc * 32 + quad * 8;
                ahi[mt] = *(const short8*)&xhi[ro];
                alo[mt] = *(const short8*)&xlo[ro];
            }
            short8 kb2[2], vbh[2], vbl[2];
#pragma unroll
            for (int nt = 0; nt < 2; nt++) {
                const int off = (32 * w + 16 * nt + l15) * 128 + kc * 32 + quad * 8;
                kb2[nt] = *(const short8*)&WKh[off];
                vbh[nt] = *(const short8*)&Wvh[off];
                vbl[nt] = *(const short8*)&Wvl[off];
            }
#pragma unroll
            for (int mt = 0; mt < 4; mt++)
#pragma unroll
                for (int nt = 0; nt < 2; nt++) {
                    acca[mt][nt] = __builtin_amdgcn_mfma_f32_16x16x32_bf16(ahi[mt], kb2[nt], acca[mt][nt], 0, 0, 0);
                    accv[mt][nt] = __builtin_amdgcn_mfma_f32_16x16x32_bf16(ahi[mt], vbh[nt], accv[mt][nt], 0, 0, 0);
                    accv[mt][nt] = __builtin_amdgcn_mfma_f32_16x16x32_bf16(ahi[mt], vbl[nt], accv[mt][nt], 0, 0, 0);
                    accv[mt][nt] = __builtin_amdgcn_mfma_f32_16x16x32_bf16(alo[mt], vbh[nt], accv[mt][nt], 0, 0, 0);
                }
        }
        __syncthreads();   // b2: xhi/xlo reads done

        // issue next tile's loads: in flight through the whole epilogue
        if (it + 1 < NT) {
            const float4* xg = (const float4*)(xbase + (size_t)(it + 1) * 64 * Fc);
#pragma unroll
            for (int i = 0; i < 8; i++) xr[i] = xg[i * 256 + t];
        }

        // v2 = expa @ vbz in two half-batches through the small eS buffer
        floatx4 acc2[4][2];
#pragma unroll
        for (int half = 0; half < 2; half++) {
#pragma unroll
            for (int mtl = 0; mtl < 2; mtl++) {
                const int mt = 2 * half + mtl;
#pragma unroll
                for (int rt = 0; rt < 2; rt++)
#pragma unroll
                    for (int reg = 0; reg < 4; reg++) {
                        const int row = 16 * mtl + 4 * quad + reg;
                        eS[row * 40 + 16 * rt + l15] =
                            f2bf(__expf((acca[mt][rt][reg] + bqkv[rt]) * SCALE));
                    }
            }
#pragma unroll
            for (int mtl = 0; mtl < 2; mtl++) {
                const int mt = 2 * half + mtl;
                short8 pa = *(const short8*)&eS[(16 * mtl + l15) * 40 + quad * 8];
#pragma unroll
                for (int dt = 0; dt < 2; dt++) {
                    acc2[mt][dt] = (floatx4)0.f;
                    acc2[mt][dt] = __builtin_amdgcn_mfma_f32_16x16x32_bf16(pa, vbz[dt], acc2[mt][dt], 0, 0, 0);
                }
            }
        }

        // out = sa*(xv+bv) + sb*v2, stored directly from C-layout.
        // Per instr: each quad writes a contiguous 64B run; L2 merges halves.
        float* op = obase + (size_t)it * 64 * Fc;
#pragma unroll
        for (int mt = 0; mt < 4; mt++)
#pragma unroll
            for (int nt = 0; nt < 2; nt++)
#pragma unroll
                for (int reg = 0; reg < 4; reg++) {
                    const int row = 16 * mt + 4 * quad + reg;
                    op[(size_t)row * 128 + w * 32 + 16 * nt + l15] =
                        sa * (accv[mt][nt][reg] + bvv[nt]) + sb * acc2[mt][nt][reg];
                }
    }
}

// ---------------------------------------------------------------------------
extern "C" void kernel_launch(void* const* d_in, const int* in_sizes, int n_in,
                              void* d_out, int out_size, void* d_ws, size_t ws_size,
                              hipStream_t stream)
{
    const float* x     = (const float*)d_in[0];
    const float* Wq    = (const float*)d_in[1];
    const float* bq    = (const float*)d_in[2];
    const float* key   = (const float*)d_in[3];
    const float* Wv    = (const float*)d_in[4];
    const float* bv    = (const float*)d_in[5];
    const float* alpha = (const float*)d_in[6];
    const float* beta  = (const float*)d_in[7];
    float* out = (float*)d_out;

    float*  ws   = (float*)d_ws;
    float*  v1   = ws + OFF_V1;
    float*  Zb   = ws + OFF_Z;
    float*  bqkp = ws + OFF_BQK;
    ushort* U    = (ushort*)(ws + OFF_U);

    hipMemsetAsync(v1, 0,
                   (size_t)(BT * Hh * Rr * Dd + BT * Hh * Rr) * sizeof(float),
                   stream);
    kprep<<<dim3(129), 256, 0, stream>>>(Wq, bq, Wv, key, U, bqkp);
    ka<<<dim3(16, BT), 256, 0, stream>>>(x, bv, U, bqkp, v1, Zb);
    kb<<<dim3(16, BT), 256, 0, stream>>>(x, bv, U, bqkp, v1, Zb, alpha, beta, out);
}

// Round 4
// 653.271 us; speedup vs baseline: 1.0667x; 1.0667x over previous
//
#include <hip/hip_runtime.h>

// Problem constants
constexpr int Nn = 4096, Fc = 128;
constexpr int Rr = 32, Hh = 4, Dd = 32;
constexpr int BT = 96;                          // B*T
constexpr float SCALE = 0.17677669529663687f;   // 1/sqrt(32)

// Workspace layout (float offsets)
constexpr size_t OFF_V1  = 0;                               // [BT][H][R][D] f32
constexpr size_t OFF_Z   = (size_t)BT * Hh * Rr * Dd;       // [BT][H][R]   f32
constexpr size_t OFF_BQK = OFF_Z + (size_t)BT * Hh * Rr;    // [H*R]        f32
constexpr size_t OFF_U   = OFF_BQK + 128;                   // param bf16 region

// U (ushort) offsets: WK hi (fused key·Wq), Wv hi, Wv lo
constexpr int U_WKHI = 0, U_WVHI = 16384, U_WVLO = 32768;

using short8  = __attribute__((ext_vector_type(8))) short;
using floatx4 = __attribute__((ext_vector_type(4))) float;

__device__ inline ushort f2bf(float f) {
    union { float f; unsigned u; } c{f};
    unsigned r = c.u + 0x7fffu + ((c.u >> 16) & 1u);  // RNE
    return (ushort)(r >> 16);
}
__device__ inline float bf2f(ushort u) {
    union { unsigned u; float f; } c{(unsigned)u << 16};
    return c.f;
}

// ---------------------------------------------------------------------------
// kprep: WK[h*32+r][f] = sum_d Wq[h*32+d][f]*key[r][h][d]  (bf16 hi)
//        Wv hi/lo split; bqk[h*32+r] = sum_d bq[h*32+d]*key[r][h][d] (f32)
// ---------------------------------------------------------------------------
__global__ void kprep(const float* __restrict__ Wq, const float* __restrict__ bq,
                      const float* __restrict__ Wv, const float* __restrict__ key,
                      ushort* __restrict__ U, float* __restrict__ bqk)
{
    const int idx = blockIdx.x * 256 + threadIdx.x;
    if (idx < 16384) {
        const int hr = idx >> 7, f = idx & 127;
        const int h = hr >> 5, r = hr & 31;
        float s = 0.f;
#pragma unroll
        for (int d = 0; d < 32; d++)
            s += Wq[(h * 32 + d) * 128 + f] * key[(r * 4 + h) * 32 + d];
        U[U_WKHI + idx] = f2bf(s);
    } else if (idx < 32768) {
        const int o = idx - 16384;
        const float v = Wv[o];
        const ushort h = f2bf(v);
        U[U_WVHI + o] = h;
        U[U_WVLO + o] = f2bf(v - bf2f(h));
    } else if (idx < 32768 + 128) {
        const int hr = idx - 32768;
        const int h = hr >> 5, r = hr & 31;
        float s = 0.f;
#pragma unroll
        for (int d = 0; d < 32; d++)
            s += bq[h * 32 + d] * key[(r * 4 + h) * 32 + d];
        bqk[hr] = s;
    }
}

// ---------------------------------------------------------------------------
// ka (pass A): NT=4 tiles of 64 nodes per block, register prefetch issued
// after the k-loop barrier, in flight through the whole epilogue.
// LDS 54272 -> 3 blocks/CU. eT/xvT both stride-72 (144 B rows, 16B-aligned
// short8 reads -> single ds_read_b128; stride-68 was misaligned for odd rows).
// ---------------------------------------------------------------------------
__global__ __launch_bounds__(256, 3)
void ka(const float* __restrict__ x, const float* __restrict__ bv,
        const ushort* __restrict__ U, const float* __restrict__ bqk,
        float* __restrict__ v1, float* __restrict__ Z)
{
    // xh [64][136] bf16 17408 | per-wave: eT [32][72] 4608 + xvT [32][72] 4608
    __shared__ __align__(16) char lds[54272];
    ushort* xh = (ushort*)lds;

    const int t = threadIdx.x;
    const int w = t >> 6, lane = t & 63;
    const int quad = lane >> 4, l15 = lane & 15;
    const int bt = blockIdx.y;
    constexpr int NT = 4;

    char* wsc = lds + 17408 + w * 9216;
    ushort* eT  = (ushort*)wsc;           // [32 r][72 n] bf16
    ushort* xvT = (ushort*)(wsc + 4608);  // [32 d][72 n] bf16

    const ushort* WKh = U + U_WKHI;
    const ushort* Wvh = U + U_WVHI;

    float bvv[2], bqkv[2];
#pragma unroll
    for (int i = 0; i < 2; i++) {
        bvv[i]  = bv[32 * w + 16 * i + l15];
        bqkv[i] = bqk[32 * w + 16 * i + l15];
    }

    floatx4 accV1[2][2];
#pragma unroll
    for (int i = 0; i < 2; i++)
#pragma unroll
        for (int j = 0; j < 2; j++) accV1[i][j] = (floatx4)0.f;
    float zacc[2] = {0.f, 0.f};

    const float* xbase = x + ((size_t)bt * Nn + blockIdx.x * (NT * 64)) * Fc;

    // prologue: tile 0 -> regs
    float4 xr[8];
#pragma unroll
    for (int i = 0; i < 8; i++) xr[i] = ((const float4*)xbase)[i * 256 + t];

#pragma unroll 1
    for (int it = 0; it < NT; ++it) {
        // regs -> LDS (waits on the prefetch issued last iteration)
#pragma unroll
        for (int i = 0; i < 8; i++) {
            const int idx = i * 256 + t;
            const int row = idx >> 5, c4 = idx & 31;
            float4 v = xr[i];
            ushort4 hv;
            hv.x = f2bf(v.x); hv.y = f2bf(v.y); hv.z = f2bf(v.z); hv.w = f2bf(v.w);
            *(ushort4*)&xh[row * 136 + c4 * 4] = hv;
        }
        __syncthreads();   // b1: tile staged

        floatx4 acca[4][2], accv[4][2];
#pragma unroll
        for (int mt = 0; mt < 4; mt++)
#pragma unroll
            for (int nt = 0; nt < 2; nt++) {
                acca[mt][nt] = (floatx4)0.f;
                accv[mt][nt] = (floatx4)0.f;
            }

#pragma unroll
        for (int kc = 0; kc < 4; kc++) {
            short8 ah[4];
#pragma unroll
            for (int mt = 0; mt < 4; mt++)
                ah[mt] = *(const short8*)&xh[(16 * mt + l15) * 136 + kc * 32 + quad * 8];
            short8 kb2[2], vb[2];
#pragma unroll
            for (int nt = 0; nt < 2; nt++) {
                const int off = (32 * w + 16 * nt + l15) * 128 + kc * 32 + quad * 8;
                kb2[nt] = *(const short8*)&WKh[off];
                vb[nt]  = *(const short8*)&Wvh[off];
            }
#pragma unroll
            for (int mt = 0; mt < 4; mt++)
#pragma unroll
                for (int nt = 0; nt < 2; nt++) {
                    acca[mt][nt] = __builtin_amdgcn_mfma_f32_16x16x32_bf16(ah[mt], kb2[nt], acca[mt][nt], 0, 0, 0);
                    accv[mt][nt] = __builtin_amdgcn_mfma_f32_16x16x32_bf16(ah[mt], vb[nt],  accv[mt][nt], 0, 0, 0);
                }
        }
        __syncthreads();   // b2: all xh reads done -> next iter may overwrite

        // issue next tile's loads: in flight through the whole epilogue
        if (it + 1 < NT) {
            const float4* xg = (const float4*)(xbase + (size_t)(it + 1) * 64 * Fc);
#pragma unroll
            for (int i = 0; i < 8; i++) xr[i] = xg[i * 256 + t];
        }

        // exp -> eT bf16 [r][n]; Z partials; per-n rowsum partials in regs
        float sloc[4][4];
#pragma unroll
        for (int mt = 0; mt < 4; mt++)
#pragma unroll
            for (int reg = 0; reg < 4; reg++) {
                const int n = 16 * mt + 4 * quad + reg;
                const float e0 = __expf((acca[mt][0][reg] + bqkv[0]) * SCALE);
                const float e1 = __expf((acca[mt][1][reg] + bqkv[1]) * SCALE);
                eT[l15 * 72 + n]        = f2bf(e0);   // r = l15
                eT[(16 + l15) * 72 + n] = f2bf(e1);   // r = 16 + l15
                zacc[0] += e0; zacc[1] += e1;
                sloc[mt][reg] = e0 + e1;
            }
        // butterfly over the 16-lane group: sloc becomes sum_r e[n][r]
#pragma unroll
        for (int m = 1; m < 16; m <<= 1)
#pragma unroll
            for (int mt = 0; mt < 4; mt++)
#pragma unroll
                for (int reg = 0; reg < 4; reg++)
                    sloc[mt][reg] += __shfl_xor(sloc[mt][reg], m);

        // xv -> xvT [d][n] bf16, pre-scaled by 1/rowsum (lane owns its n's sum)
#pragma unroll
        for (int mt = 0; mt < 4; mt++)
#pragma unroll
            for (int reg = 0; reg < 4; reg++) {
                const int n = 16 * mt + 4 * quad + reg;
                const float sw = 1.f / sloc[mt][reg];
#pragma unroll
                for (int nt = 0; nt < 2; nt++)
                    xvT[(16 * nt + l15) * 72 + n] =
                        f2bf((accv[mt][nt][reg] + bvv[nt]) * sw);
            }

        // v1[r][d] += sum_n eT[r][n] * xvT[d][n]
#pragma unroll
        for (int kn = 0; kn < 2; kn++) {
            short8 ae[2], bx[2];
#pragma unroll
            for (int i = 0; i < 2; i++) {
                ae[i] = *(const short8*)&eT[(16 * i + l15) * 72 + kn * 32 + quad * 8];
                bx[i] = *(const short8*)&xvT[(16 * i + l15) * 72 + kn * 32 + quad * 8];
            }
#pragma unroll
            for (int mt = 0; mt < 2; mt++)
#pragma unroll
                for (int nt = 0; nt < 2; nt++)
                    accV1[mt][nt] = __builtin_amdgcn_mfma_f32_16x16x32_bf16(ae[mt], bx[nt], accV1[mt][nt], 0, 0, 0);
        }
    }

    // Z: reduce over quads, atomic once per col
#pragma unroll
    for (int rt = 0; rt < 2; rt++) {
        float zr = zacc[rt];
        zr += __shfl_xor(zr, 16);
        zr += __shfl_xor(zr, 32);
        if (quad == 0)
            atomicAdd(&Z[((size_t)bt * Hh + w) * Rr + 16 * rt + l15], zr);
    }
    float* v1b = v1 + ((size_t)bt * Hh + w) * Rr * Dd;
#pragma unroll
    for (int mt = 0; mt < 2; mt++)
#pragma unroll
        for (int nt = 0; nt < 2; nt++)
#pragma unroll
            for (int reg = 0; reg < 4; reg++)
                atomicAdd(&v1b[(16 * mt + 4 * quad + reg) * 32 + 16 * nt + l15],
                          accV1[mt][nt][reg]);
}

// ---------------------------------------------------------------------------
// kb (pass B): recompute attn + xv (hi/lo), v2 = expa @ (v1/Z) via MFMA.
// k2b folded in (vbz built from v1/Z once per block). Output goes through a
// per-wave f32 LDS buffer in TWO 32-row halves -> dense float4 stores
// (128 B contiguous per row): full-line writebacks, no partial-line RMW.
// (Round 3's direct C-layout scalar stores doubled HBM traffic: 64 B
//  fragments per instruction caused read-modify-write — reverted.)
// LDS 53248 -> 3 blocks/CU.
// ---------------------------------------------------------------------------
__global__ __launch_bounds__(256, 3)
void kb(const float* __restrict__ x, const float* __restrict__ bv,
        const ushort* __restrict__ U, const float* __restrict__ bqk,
        const float* __restrict__ v1, const float* __restrict__ Z,
        const float* __restrict__ alpha, const float* __restrict__ beta,
        float* __restrict__ out)
{
    // xhi [64][136] 17408 | xlo 17408 | 4x per-wave scratch 4608
    __shared__ __align__(16) char lds[53248];
    ushort* xhi = (ushort*)lds;
    ushort* xlo = (ushort*)(lds + 17408);

    const int t = threadIdx.x;
    const int w = t >> 6, lane = t & 63;
    const int quad = lane >> 4, l15 = lane & 15;
    const int bt = blockIdx.y;
    constexpr int NT = 4;

    char* wsc = lds + 34816 + w * 4608;
    ushort* eS = (ushort*)wsc;   // [32][40] bf16 (2560 B)
    float*  fS = (float*)wsc;    // [32][36] f32 (4608 B) overlay; stride 144 B
                                 // keeps float4 rows 16B-aligned

    const ushort* WKh = U + U_WKHI;
    const ushort* Wvh = U + U_WVHI;
    const ushort* Wvl = U + U_WVLO;

    float bqkv[2], bvv[2];
#pragma unroll
    for (int i = 0; i < 2; i++) {
        bqkv[i] = bqk[32 * w + 16 * i + l15];
        bvv[i]  = bv[32 * w + 16 * i + l15];
    }

    // build vbz B-frag: vbz[dt] lane(q,l15) = bf16(v1[r=8q+j][d=16dt+l15]/Z[r])
    const float* v1h = v1 + ((size_t)bt * Hh + w) * Rr * Dd;
    const float* Zh  = Z + ((size_t)bt * Hh + w) * Rr;
    float zr8[8];
#pragma unroll
    for (int j = 0; j < 8; j++) zr8[j] = 1.f / Zh[8 * quad + j];
    short8 vbz[2];
#pragma unroll
    for (int dt = 0; dt < 2; dt++) {
        union { short8 s; unsigned u[4]; } uu;
#pragma unroll
        for (int jj = 0; jj < 4; jj++) {
            const float a0 = v1h[(8 * quad + 2 * jj) * 32 + 16 * dt + l15] * zr8[2 * jj];
            const float a1 = v1h[(8 * quad + 2 * jj + 1) * 32 + 16 * dt + l15] * zr8[2 * jj + 1];
            uu.u[jj] = ((unsigned)f2bf(a1) << 16) | f2bf(a0);
        }
        vbz[dt] = uu.s;
    }
    const float sa = 1.f / (1.f + __expf(-alpha[w]));
    const float sb = 1.f / (1.f + __expf(-beta[w]));

    const float* xbase = x + ((size_t)bt * Nn + blockIdx.x * (NT * 64)) * Fc;
    float* obase = out + ((size_t)bt * Nn + blockIdx.x * (NT * 64)) * Fc;

    float4 xr[8];
#pragma unroll
    for (int i = 0; i < 8; i++) xr[i] = ((const float4*)xbase)[i * 256 + t];

#pragma unroll 1
    for (int it = 0; it < NT; ++it) {
        // regs -> LDS hi/lo (waits on prefetch)
#pragma unroll
        for (int i = 0; i < 8; i++) {
            const int idx = i * 256 + t;
            const int row = idx >> 5, c4 = idx & 31;
            float4 v = xr[i];
            ushort h0 = f2bf(v.x), h1 = f2bf(v.y), h2 = f2bf(v.z), h3 = f2bf(v.w);
            ushort4 hv; hv.x = h0; hv.y = h1; hv.z = h2; hv.w = h3;
            ushort4 lv; lv.x = f2bf(v.x - bf2f(h0)); lv.y = f2bf(v.y - bf2f(h1));
            lv.z = f2bf(v.z - bf2f(h2)); lv.w = f2bf(v.w - bf2f(h3));
            *(ushort4*)&xhi[row * 136 + c4 * 4] = hv;
            *(ushort4*)&xlo[row * 136 + c4 * 4] = lv;
        }
        __syncthreads();   // b1

        floatx4 acca[4][2], accv[4][2];
#pragma unroll
        for (int mt = 0; mt < 4; mt++)
#pragma unroll
            for (int nt = 0; nt < 2; nt++) {
                acca[mt][nt] = (floatx4)0.f;
                accv[mt][nt] = (floatx4)0.f;
            }

#pragma unroll
        for (int kc = 0; kc < 4; kc++) {
            short8 ahi[4], alo[4];
#pragma unroll
            for (int mt = 0; mt < 4; mt++) {
                const int ro = (16 * mt + l15) * 136 + kc * 32 + quad * 8;
                ahi[mt] = *(const short8*)&xhi[ro];
                alo[mt] = *(const short8*)&xlo[ro];
            }
            short8 kb2[2], vbh[2], vbl[2];
#pragma unroll
            for (int nt = 0; nt < 2; nt++) {
                const int off = (32 * w + 16 * nt + l15) * 128 + kc * 32 + quad * 8;
                kb2[nt] = *(const short8*)&WKh[off];
                vbh[nt] = *(const short8*)&Wvh[off];
                vbl[nt] = *(const short8*)&Wvl[off];
            }
#pragma unroll
            for (int mt = 0; mt < 4; mt++)
#pragma unroll
                for (int nt = 0; nt < 2; nt++) {
                    acca[mt][nt] = __builtin_amdgcn_mfma_f32_16x16x32_bf16(ahi[mt], kb2[nt], acca[mt][nt], 0, 0, 0);
                    accv[mt][nt] = __builtin_amdgcn_mfma_f32_16x16x32_bf16(ahi[mt], vbh[nt], accv[mt][nt], 0, 0, 0);
                    accv[mt][nt] = __builtin_amdgcn_mfma_f32_16x16x32_bf16(ahi[mt], vbl[nt], accv[mt][nt], 0, 0, 0);
                    accv[mt][nt] = __builtin_amdgcn_mfma_f32_16x16x32_bf16(alo[mt], vbh[nt], accv[mt][nt], 0, 0, 0);
                }
        }
        __syncthreads();   // b2: xhi/xlo reads done

        // issue next tile's loads: in flight through the whole epilogue
        if (it + 1 < NT) {
            const float4* xg = (const float4*)(xbase + (size_t)(it + 1) * 64 * Fc);
#pragma unroll
            for (int i = 0; i < 8; i++) xr[i] = xg[i * 256 + t];
        }

        float* op = obase + (size_t)it * 64 * Fc;

        // two 32-row halves: exp->eS->v2 MFMA, mix->fS, dense float4 stores.
        // eS/fS overlay is safe: per-wave DS ops are in-order.
#pragma unroll
        for (int half = 0; half < 2; half++) {
#pragma unroll
            for (int mtl = 0; mtl < 2; mtl++) {
                const int mt = 2 * half + mtl;
#pragma unroll
                for (int rt = 0; rt < 2; rt++)
#pragma unroll
                    for (int reg = 0; reg < 4; reg++) {
                        const int row = 16 * mtl + 4 * quad + reg;
                        eS[row * 40 + 16 * rt + l15] =
                            f2bf(__expf((acca[mt][rt][reg] + bqkv[rt]) * SCALE));
                    }
            }
            floatx4 acc2[2][2];
#pragma unroll
            for (int mtl = 0; mtl < 2; mtl++) {
                short8 pa = *(const short8*)&eS[(16 * mtl + l15) * 40 + quad * 8];
#pragma unroll
                for (int dt = 0; dt < 2; dt++) {
                    acc2[mtl][dt] = (floatx4)0.f;
                    acc2[mtl][dt] = __builtin_amdgcn_mfma_f32_16x16x32_bf16(pa, vbz[dt], acc2[mtl][dt], 0, 0, 0);
                }
            }
#pragma unroll
            for (int mtl = 0; mtl < 2; mtl++) {
                const int mt = 2 * half + mtl;
#pragma unroll
                for (int nt = 0; nt < 2; nt++)
#pragma unroll
                    for (int reg = 0; reg < 4; reg++) {
                        const int row = 16 * mtl + 4 * quad + reg;
                        fS[row * 36 + 16 * nt + l15] =
                            sa * (accv[mt][nt][reg] + bvv[nt]) + sb * acc2[mtl][nt][reg];
                    }
            }
#pragma unroll
            for (int i = 0; i < 4; i++) {
                const int idx = i * 64 + lane;
                const int n = idx >> 3, c4 = idx & 7;
                *(float4*)&op[(size_t)(32 * half + n) * 128 + w * 32 + c4 * 4] =
                    *(const float4*)&fS[n * 36 + c4 * 4];
            }
        }
    }
}

// ---------------------------------------------------------------------------
extern "C" void kernel_launch(void* const* d_in, const int* in_sizes, int n_in,
                              void* d_out, int out_size, void* d_ws, size_t ws_size,
                              hipStream_t stream)
{
    const float* x     = (const float*)d_in[0];
    const float* Wq    = (const float*)d_in[1];
    const float* bq    = (const float*)d_in[2];
    const float* key   = (const float*)d_in[3];
    const float* Wv    = (const float*)d_in[4];
    const float* bv    = (const float*)d_in[5];
    const float* alpha = (const float*)d_in[6];
    const float* beta  = (const float*)d_in[7];
    float* out = (float*)d_out;

    float*  ws   = (float*)d_ws;
    float*  v1   = ws + OFF_V1;
    float*  Zb   = ws + OFF_Z;
    float*  bqkp = ws + OFF_BQK;
    ushort* U    = (ushort*)(ws + OFF_U);

    hipMemsetAsync(v1, 0,
                   (size_t)(BT * Hh * Rr * Dd + BT * Hh * Rr) * sizeof(float),
                   stream);
    kprep<<<dim3(129), 256, 0, stream>>>(Wq, bq, Wv, key, U, bqkp);
    ka<<<dim3(16, BT), 256, 0, stream>>>(x, bv, U, bqkp, v1, Zb);
    kb<<<dim3(16, BT), 256, 0, stream>>>(x, bv, U, bqkp, v1, Zb, alpha, beta, out);
}

// Round 5
// 486.760 us; speedup vs baseline: 1.4316x; 1.3421x over previous
//
#include <hip/hip_runtime.h>

// Problem constants
constexpr int Nn = 4096, Fc = 128;
constexpr int Rr = 32, Hh = 4, Dd = 32;
constexpr int BT = 96;                          // B*T
constexpr float SCALE = 0.17677669529663687f;   // 1/sqrt(32)

// Workspace layout (float offsets)
constexpr size_t OFF_V1  = 0;                               // [BT][H][R][D] f32
constexpr size_t OFF_Z   = (size_t)BT * Hh * Rr * Dd;       // [BT][H][R]   f32
constexpr size_t OFF_BQK = OFF_Z + (size_t)BT * Hh * Rr;    // [H*R]        f32
constexpr size_t OFF_U   = OFF_BQK + 128;                   // param bf16 region

// U (ushort) offsets: WK hi (fused key·Wq), Wv hi, Wv lo
constexpr int U_WKHI = 0, U_WVHI = 16384, U_WVLO = 32768;

using short8  = __attribute__((ext_vector_type(8))) short;
using floatx4 = __attribute__((ext_vector_type(4))) float;

__device__ inline ushort f2bf(float f) {
    union { float f; unsigned u; } c{f};
    unsigned r = c.u + 0x7fffu + ((c.u >> 16) & 1u);  // RNE
    return (ushort)(r >> 16);
}
__device__ inline float bf2f(ushort u) {
    union { unsigned u; float f; } c{(unsigned)u << 16};
    return c.f;
}

// ---------------------------------------------------------------------------
// kprep: WK[h*32+r][f] = sum_d Wq[h*32+d][f]*key[r][h][d]  (bf16 hi)
//        Wv hi/lo split; bqk[h*32+r] = sum_d bq[h*32+d]*key[r][h][d] (f32)
// ---------------------------------------------------------------------------
__global__ void kprep(const float* __restrict__ Wq, const float* __restrict__ bq,
                      const float* __restrict__ Wv, const float* __restrict__ key,
                      ushort* __restrict__ U, float* __restrict__ bqk)
{
    const int idx = blockIdx.x * 256 + threadIdx.x;
    if (idx < 16384) {
        const int hr = idx >> 7, f = idx & 127;
        const int h = hr >> 5, r = hr & 31;
        float s = 0.f;
#pragma unroll
        for (int d = 0; d < 32; d++)
            s += Wq[(h * 32 + d) * 128 + f] * key[(r * 4 + h) * 32 + d];
        U[U_WKHI + idx] = f2bf(s);
    } else if (idx < 32768) {
        const int o = idx - 16384;
        const float v = Wv[o];
        const ushort h = f2bf(v);
        U[U_WVHI + o] = h;
        U[U_WVLO + o] = f2bf(v - bf2f(h));
    } else if (idx < 32768 + 128) {
        const int hr = idx - 32768;
        const int h = hr >> 5, r = hr & 31;
        float s = 0.f;
#pragma unroll
        for (int d = 0; d < 32; d++)
            s += bq[h * 32 + d] * key[(r * 4 + h) * 32 + d];
        bqk[hr] = s;
    }
}

// ---------------------------------------------------------------------------
// ka (pass A): NT=4 tiles/block, register prefetch, DOUBLE-buffered x LDS ->
// one barrier per iteration. __launch_bounds__(256,2): unified VGPR+AGPR
// budget 256/wave -> NO SPILLS (the (256,3) variant capped the budget at
// ~170, spilled xr/operands to scratch, and paid ~200 MB of HBM traffic).
// ---------------------------------------------------------------------------
__global__ __launch_bounds__(256, 2)
void ka(const float* __restrict__ x, const float* __restrict__ bv,
        const ushort* __restrict__ U, const float* __restrict__ bqk,
        float* __restrict__ v1, float* __restrict__ Z)
{
    // xh x2 [64][136] bf16 (2*17408) | per-wave: eT [32][72], xvT [32][72]
    __shared__ __align__(16) char lds[71680];

    const int t = threadIdx.x;
    const int w = t >> 6, lane = t & 63;
    const int quad = lane >> 4, l15 = lane & 15;
    const int bt = blockIdx.y;
    constexpr int NT = 4;

    char* wsc = lds + 34816 + w * 9216;
    ushort* eT  = (ushort*)wsc;           // [32 r][72 n] bf16
    ushort* xvT = (ushort*)(wsc + 4608);  // [32 d][72 n] bf16 (xv*srw)

    const ushort* WKh = U + U_WKHI;
    const ushort* Wvh = U + U_WVHI;

    float bvv[2], bqkv[2];
#pragma unroll
    for (int i = 0; i < 2; i++) {
        bvv[i]  = bv[32 * w + 16 * i + l15];
        bqkv[i] = bqk[32 * w + 16 * i + l15];
    }

    floatx4 accV1[2][2];
#pragma unroll
    for (int i = 0; i < 2; i++)
#pragma unroll
        for (int j = 0; j < 2; j++) accV1[i][j] = (floatx4)0.f;
    float zacc[2] = {0.f, 0.f};

    const float* xbase = x + ((size_t)bt * Nn + blockIdx.x * (NT * 64)) * Fc;

    // prologue: tile 0 -> regs
    float4 xr[8];
#pragma unroll
    for (int i = 0; i < 8; i++) xr[i] = ((const float4*)xbase)[i * 256 + t];

#pragma unroll 1
    for (int it = 0; it < NT; ++it) {
        ushort* xh = (ushort*)(lds + (it & 1) * 17408);
        // regs -> LDS (waits on the prefetch issued last iteration)
#pragma unroll
        for (int i = 0; i < 8; i++) {
            const int idx = i * 256 + t;
            const int row = idx >> 5, c4 = idx & 31;
            float4 v = xr[i];
            ushort4 hv;
            hv.x = f2bf(v.x); hv.y = f2bf(v.y); hv.z = f2bf(v.z); hv.w = f2bf(v.w);
            *(ushort4*)&xh[row * 136 + c4 * 4] = hv;
        }
        __syncthreads();   // single barrier per iteration (double-buffered xh)

        floatx4 acca[4][2], accv[4][2];
#pragma unroll
        for (int mt = 0; mt < 4; mt++)
#pragma unroll
            for (int nt = 0; nt < 2; nt++) {
                acca[mt][nt] = (floatx4)0.f;
                accv[mt][nt] = (floatx4)0.f;
            }

#pragma unroll
        for (int kc = 0; kc < 4; kc++) {
            short8 ah[4];
#pragma unroll
            for (int mt = 0; mt < 4; mt++)
                ah[mt] = *(const short8*)&xh[(16 * mt + l15) * 136 + kc * 32 + quad * 8];
            short8 kb2[2], vb[2];
#pragma unroll
            for (int nt = 0; nt < 2; nt++) {
                const int off = (32 * w + 16 * nt + l15) * 128 + kc * 32 + quad * 8;
                kb2[nt] = *(const short8*)&WKh[off];
                vb[nt]  = *(const short8*)&Wvh[off];
            }
#pragma unroll
            for (int mt = 0; mt < 4; mt++)
#pragma unroll
                for (int nt = 0; nt < 2; nt++) {
                    acca[mt][nt] = __builtin_amdgcn_mfma_f32_16x16x32_bf16(ah[mt], kb2[nt], acca[mt][nt], 0, 0, 0);
                    accv[mt][nt] = __builtin_amdgcn_mfma_f32_16x16x32_bf16(ah[mt], vb[nt],  accv[mt][nt], 0, 0, 0);
                }
        }

        // issue next tile's loads NOW: they fly during the whole epilogue
        if (it + 1 < NT) {
            const float4* xg = (const float4*)(xbase + (size_t)(it + 1) * 64 * Fc);
#pragma unroll
            for (int i = 0; i < 8; i++) xr[i] = xg[i * 256 + t];
        }

        // exp -> eT bf16 [r][n]; Z partials; per-n rowsum partials in regs
        float sloc[4][4];
#pragma unroll
        for (int mt = 0; mt < 4; mt++)
#pragma unroll
            for (int reg = 0; reg < 4; reg++) {
                const int n = 16 * mt + 4 * quad + reg;
                const float e0 = __expf((acca[mt][0][reg] + bqkv[0]) * SCALE);
                const float e1 = __expf((acca[mt][1][reg] + bqkv[1]) * SCALE);
                eT[l15 * 72 + n]        = f2bf(e0);   // r = l15
                eT[(16 + l15) * 72 + n] = f2bf(e1);   // r = 16 + l15
                zacc[0] += e0; zacc[1] += e1;
                sloc[mt][reg] = e0 + e1;
            }
        // butterfly over the 16-lane group: sloc becomes sum_r e[n][r]
#pragma unroll
        for (int m = 1; m < 16; m <<= 1)
#pragma unroll
            for (int mt = 0; mt < 4; mt++)
#pragma unroll
                for (int reg = 0; reg < 4; reg++)
                    sloc[mt][reg] += __shfl_xor(sloc[mt][reg], m);

        // xv -> xvT [d][n] bf16, pre-scaled by 1/rowsum (lane owns its n's sum)
#pragma unroll
        for (int mt = 0; mt < 4; mt++)
#pragma unroll
            for (int reg = 0; reg < 4; reg++) {
                const int n = 16 * mt + 4 * quad + reg;
                const float sw = 1.f / sloc[mt][reg];
#pragma unroll
                for (int nt = 0; nt < 2; nt++)
                    xvT[(16 * nt + l15) * 72 + n] =
                        f2bf((accv[mt][nt][reg] + bvv[nt]) * sw);
            }

        // v1[r][d] += sum_n eT[r][n] * xvT[d][n]
#pragma unroll
        for (int kn = 0; kn < 2; kn++) {
            short8 ae[2], bx[2];
#pragma unroll
            for (int i = 0; i < 2; i++) {
                ae[i] = *(const short8*)&eT[(16 * i + l15) * 72 + kn * 32 + quad * 8];
                bx[i] = *(const short8*)&xvT[(16 * i + l15) * 72 + kn * 32 + quad * 8];
            }
#pragma unroll
            for (int mt = 0; mt < 2; mt++)
#pragma unroll
                for (int nt = 0; nt < 2; nt++)
                    accV1[mt][nt] = __builtin_amdgcn_mfma_f32_16x16x32_bf16(ae[mt], bx[nt], accV1[mt][nt], 0, 0, 0);
        }
    }

    // Z: reduce over quads, atomic once per col
#pragma unroll
    for (int rt = 0; rt < 2; rt++) {
        float zr = zacc[rt];
        zr += __shfl_xor(zr, 16);
        zr += __shfl_xor(zr, 32);
        if (quad == 0)
            atomicAdd(&Z[((size_t)bt * Hh + w) * Rr + 16 * rt + l15], zr);
    }
    float* v1b = v1 + ((size_t)bt * Hh + w) * Rr * Dd;
#pragma unroll
    for (int mt = 0; mt < 2; mt++)
#pragma unroll
        for (int nt = 0; nt < 2; nt++)
#pragma unroll
            for (int reg = 0; reg < 4; reg++)
                atomicAdd(&v1b[(16 * mt + 4 * quad + reg) * 32 + 16 * nt + l15],
                          accV1[mt][nt][reg]);
}

// ---------------------------------------------------------------------------
// kb (pass B): recompute attn + xv (hi/lo), v2 = expa @ (v1/Z) via MFMA.
// k2b fused (vbz built from v1/Z once per block). Output via per-wave f32
// LDS buffer in two 32-row halves -> dense float4 stores (full-line
// writebacks). __launch_bounds__(256,2): no spills (see ka comment).
// LDS 53248; occupancy 2-3 blocks/CU depending on final register count.
// ---------------------------------------------------------------------------
__global__ __launch_bounds__(256, 2)
void kb(const float* __restrict__ x, const float* __restrict__ bv,
        const ushort* __restrict__ U, const float* __restrict__ bqk,
        const float* __restrict__ v1, const float* __restrict__ Z,
        const float* __restrict__ alpha, const float* __restrict__ beta,
        float* __restrict__ out)
{
    // xhi [64][136] 17408 | xlo 17408 | 4x per-wave scratch 4608
    __shared__ __align__(16) char lds[53248];
    ushort* xhi = (ushort*)lds;
    ushort* xlo = (ushort*)(lds + 17408);

    const int t = threadIdx.x;
    const int w = t >> 6, lane = t & 63;
    const int quad = lane >> 4, l15 = lane & 15;
    const int bt = blockIdx.y;
    constexpr int NT = 4;

    char* wsc = lds + 34816 + w * 4608;
    ushort* eS = (ushort*)wsc;   // [32][40] bf16 (2560 B)
    float*  fS = (float*)wsc;    // [32][36] f32 (4608 B) overlay, 144 B rows

    const ushort* WKh = U + U_WKHI;
    const ushort* Wvh = U + U_WVHI;
    const ushort* Wvl = U + U_WVLO;

    float bqkv[2], bvv[2];
#pragma unroll
    for (int i = 0; i < 2; i++) {
        bqkv[i] = bqk[32 * w + 16 * i + l15];
        bvv[i]  = bv[32 * w + 16 * i + l15];
    }

    // build vbz B-frag: vbz[dt] lane(q,l15) = bf16(v1[r=8q+j][d=16dt+l15]/Z[r])
    const float* v1h = v1 + ((size_t)bt * Hh + w) * Rr * Dd;
    const float* Zh  = Z + ((size_t)bt * Hh + w) * Rr;
    float zr8[8];
#pragma unroll
    for (int j = 0; j < 8; j++) zr8[j] = 1.f / Zh[8 * quad + j];
    short8 vbz[2];
#pragma unroll
    for (int dt = 0; dt < 2; dt++) {
        union { short8 s; unsigned u[4]; } uu;
#pragma unroll
        for (int jj = 0; jj < 4; jj++) {
            const float a0 = v1h[(8 * quad + 2 * jj) * 32 + 16 * dt + l15] * zr8[2 * jj];
            const float a1 = v1h[(8 * quad + 2 * jj + 1) * 32 + 16 * dt + l15] * zr8[2 * jj + 1];
            uu.u[jj] = ((unsigned)f2bf(a1) << 16) | f2bf(a0);
        }
        vbz[dt] = uu.s;
    }
    const float sa = 1.f / (1.f + __expf(-alpha[w]));
    const float sb = 1.f / (1.f + __expf(-beta[w]));

    const float* xbase = x + ((size_t)bt * Nn + blockIdx.x * (NT * 64)) * Fc;
    float* obase = out + ((size_t)bt * Nn + blockIdx.x * (NT * 64)) * Fc;

    float4 xr[8];
#pragma unroll
    for (int i = 0; i < 8; i++) xr[i] = ((const float4*)xbase)[i * 256 + t];

#pragma unroll 1
    for (int it = 0; it < NT; ++it) {
        // regs -> LDS hi/lo (waits on prefetch)
#pragma unroll
        for (int i = 0; i < 8; i++) {
            const int idx = i * 256 + t;
            const int row = idx >> 5, c4 = idx & 31;
            float4 v = xr[i];
            ushort h0 = f2bf(v.x), h1 = f2bf(v.y), h2 = f2bf(v.z), h3 = f2bf(v.w);
            ushort4 hv; hv.x = h0; hv.y = h1; hv.z = h2; hv.w = h3;
            ushort4 lv; lv.x = f2bf(v.x - bf2f(h0)); lv.y = f2bf(v.y - bf2f(h1));
            lv.z = f2bf(v.z - bf2f(h2)); lv.w = f2bf(v.w - bf2f(h3));
            *(ushort4*)&xhi[row * 136 + c4 * 4] = hv;
            *(ushort4*)&xlo[row * 136 + c4 * 4] = lv;
        }
        __syncthreads();   // b1

        floatx4 acca[4][2], accv[4][2];
#pragma unroll
        for (int mt = 0; mt < 4; mt++)
#pragma unroll
            for (int nt = 0; nt < 2; nt++) {
                acca[mt][nt] = (floatx4)0.f;
                accv[mt][nt] = (floatx4)0.f;
            }

#pragma unroll
        for (int kc = 0; kc < 4; kc++) {
            short8 ahi[4], alo[4];
#pragma unroll
            for (int mt = 0; mt < 4; mt++) {
                const int ro = (16 * mt + l15) * 136 + kc * 32 + quad * 8;
                ahi[mt] = *(const short8*)&xhi[ro];
                alo[mt] = *(const short8*)&xlo[ro];
            }
            short8 kb2[2], vbh[2], vbl[2];
#pragma unroll
            for (int nt = 0; nt < 2; nt++) {
                const int off = (32 * w + 16 * nt + l15) * 128 + kc * 32 + quad * 8;
                kb2[nt] = *(const short8*)&WKh[off];
                vbh[nt] = *(const short8*)&Wvh[off];
                vbl[nt] = *(const short8*)&Wvl[off];
            }
#pragma unroll
            for (int mt = 0; mt < 4; mt++)
#pragma unroll
                for (int nt = 0; nt < 2; nt++) {
                    acca[mt][nt] = __builtin_amdgcn_mfma_f32_16x16x32_bf16(ahi[mt], kb2[nt], acca[mt][nt], 0, 0, 0);
                    accv[mt][nt] = __builtin_amdgcn_mfma_f32_16x16x32_bf16(ahi[mt], vbh[nt], accv[mt][nt], 0, 0, 0);
                    accv[mt][nt] = __builtin_amdgcn_mfma_f32_16x16x32_bf16(ahi[mt], vbl[nt], accv[mt][nt], 0, 0, 0);
                    accv[mt][nt] = __builtin_amdgcn_mfma_f32_16x16x32_bf16(alo[mt], vbh[nt], accv[mt][nt], 0, 0, 0);
                }
        }
        __syncthreads();   // b2: xhi/xlo reads done

        // issue next tile's loads: in flight through the whole epilogue
        if (it + 1 < NT) {
            const float4* xg = (const float4*)(xbase + (size_t)(it + 1) * 64 * Fc);
#pragma unroll
            for (int i = 0; i < 8; i++) xr[i] = xg[i * 256 + t];
        }

        float* op = obase + (size_t)it * 64 * Fc;

        // two 32-row halves: exp->eS->v2 MFMA, mix->fS, dense float4 stores.
        // eS/fS overlay safe: per-wave DS ops are in-order.
#pragma unroll
        for (int half = 0; half < 2; half++) {
#pragma unroll
            for (int mtl = 0; mtl < 2; mtl++) {
                const int mt = 2 * half + mtl;
#pragma unroll
                for (int rt = 0; rt < 2; rt++)
#pragma unroll
                    for (int reg = 0; reg < 4; reg++) {
                        const int row = 16 * mtl + 4 * quad + reg;
                        eS[row * 40 + 16 * rt + l15] =
                            f2bf(__expf((acca[mt][rt][reg] + bqkv[rt]) * SCALE));
                    }
            }
            floatx4 acc2[2][2];
#pragma unroll
            for (int mtl = 0; mtl < 2; mtl++) {
                short8 pa = *(const short8*)&eS[(16 * mtl + l15) * 40 + quad * 8];
#pragma unroll
                for (int dt = 0; dt < 2; dt++) {
                    acc2[mtl][dt] = (floatx4)0.f;
                    acc2[mtl][dt] = __builtin_amdgcn_mfma_f32_16x16x32_bf16(pa, vbz[dt], acc2[mtl][dt], 0, 0, 0);
                }
            }
#pragma unroll
            for (int mtl = 0; mtl < 2; mtl++) {
                const int mt = 2 * half + mtl;
#pragma unroll
                for (int nt = 0; nt < 2; nt++)
#pragma unroll
                    for (int reg = 0; reg < 4; reg++) {
                        const int row = 16 * mtl + 4 * quad + reg;
                        fS[row * 36 + 16 * nt + l15] =
                            sa * (accv[mt][nt][reg] + bvv[nt]) + sb * acc2[mtl][nt][reg];
                    }
            }
#pragma unroll
            for (int i = 0; i < 4; i++) {
                const int idx = i * 64 + lane;
                const int n = idx >> 3, c4 = idx & 7;
                *(float4*)&op[(size_t)(32 * half + n) * 128 + w * 32 + c4 * 4] =
                    *(const float4*)&fS[n * 36 + c4 * 4];
            }
        }
    }
}

// ---------------------------------------------------------------------------
extern "C" void kernel_launch(void* const* d_in, const int* in_sizes, int n_in,
                              void* d_out, int out_size, void* d_ws, size_t ws_size,
                              hipStream_t stream)
{
    const float* x     = (const float*)d_in[0];
    const float* Wq    = (const float*)d_in[1];
    const float* bq    = (const float*)d_in[2];
    const float* key   = (const float*)d_in[3];
    const float* Wv    = (const float*)d_in[4];
    const float* bv    = (const float*)d_in[5];
    const float* alpha = (const float*)d_in[6];
    const float* beta  = (const float*)d_in[7];
    float* out = (float*)d_out;

    float*  ws   = (float*)d_ws;
    float*  v1   = ws + OFF_V1;
    float*  Zb   = ws + OFF_Z;
    float*  bqkp = ws + OFF_BQK;
    ushort* U    = (ushort*)(ws + OFF_U);

    hipMemsetAsync(v1, 0,
                   (size_t)(BT * Hh * Rr * Dd + BT * Hh * Rr) * sizeof(float),
                   stream);
    kprep<<<dim3(129), 256, 0, stream>>>(Wq, bq, Wv, key, U, bqkp);
    ka<<<dim3(16, BT), 256, 0, stream>>>(x, bv, U, bqkp, v1, Zb);
    kb<<<dim3(16, BT), 256, 0, stream>>>(x, bv, U, bqkp, v1, Zb, alpha, beta, out);
}